// Round 5
// baseline (172.533 us; speedup 1.0000x reference)
//
#include <hip/hip_runtime.h>

// SimGRew: Wmat = relu(S - prob + 0.5*A_sel) * same-graph-block mask
//   S = (X_hat @ X_hat^T) / ||X_hat||_F^2,  X_hat = x @ W0^T + b0
//   A_sel[i,j] = A[batch[i], i, j] (local-index adjacency) -> nonzero only for
//   i,j < NPG: ONLY graph 0's diagonal block sees the +alpha*A term.
// Outputs flat: Wmat[N*N] f32, edge_ratio, prob.
//
// R5: 2 dispatches. Graph-0 diag tiles build their 64x64 adjacency tile in LDS
// by scanning the (L2-resident, 1MB) edge list directly — no global Acnt, no
// scatter dispatch, no zeroing dispatch. Final scalars via agent-scope atomics
// from tid0 of the 512 diag blocks only (NOT the R2 all-thread threadfence).

#define NN   4096
#define GG   8
#define NPG  512
#define FF   128
#define HH   128
#define NE   131072
#define ALPHA 0.5f

// ws layout (bytes):
//   [0,8)        meta   u32 nz, u32 done   (zeroed by k_xhat block 128)
//   [64,576)     normp  float[128]         (per-xhat-block norm partials)
//   [4096, +2MB) Xh     float[NN*HH]
#define NORMP_OFF 64
#define XH_OFF    4096

// blocks 0..127: X_hat 64x64 tiles (Xh + normp[bx]); block 128: zero meta.
__global__ __launch_bounds__(256) void k_xhat(const float* __restrict__ x,
                                              const float* __restrict__ W0,
                                              const float* __restrict__ b0,
                                              float* __restrict__ Xh,
                                              float* __restrict__ normp,
                                              unsigned* __restrict__ meta) {
    int bx = blockIdx.x;
    int tid = threadIdx.x;

    if (bx == 128) {
        if (tid < 2) meta[tid] = 0u;
        return;
    }

    __shared__ float As[16][68];
    __shared__ float Bs[16][68];
    __shared__ float red[256];

    int tm = bx >> 1, tn = bx & 1;
    int r0 = tm * 64, j0 = tn * 64;
    int tx = tid & 15, ty = tid >> 4;
    int li = tid & 63, kq = tid >> 6;

    float acc[4][4];
#pragma unroll
    for (int i = 0; i < 4; ++i)
#pragma unroll
        for (int j = 0; j < 4; ++j) acc[i][j] = 0.f;

    for (int k0 = 0; k0 < FF; k0 += 16) {
        float4 av = *(const float4*)&x [(size_t)(r0 + li) * FF + k0 + kq * 4];
        float4 bv = *(const float4*)&W0[(size_t)(j0 + li) * FF + k0 + kq * 4];
        As[kq*4+0][li] = av.x; As[kq*4+1][li] = av.y;
        As[kq*4+2][li] = av.z; As[kq*4+3][li] = av.w;
        Bs[kq*4+0][li] = bv.x; Bs[kq*4+1][li] = bv.y;
        Bs[kq*4+2][li] = bv.z; Bs[kq*4+3][li] = bv.w;
        __syncthreads();
#pragma unroll
        for (int k = 0; k < 16; ++k) {
            float4 a = *(const float4*)&As[k][ty * 4];
            float4 b = *(const float4*)&Bs[k][tx * 4];
            float ar[4] = {a.x, a.y, a.z, a.w};
            float br[4] = {b.x, b.y, b.z, b.w};
#pragma unroll
            for (int i = 0; i < 4; ++i)
#pragma unroll
                for (int j = 0; j < 4; ++j) acc[i][j] += ar[i] * br[j];
        }
        __syncthreads();
    }

    float4 bb = *(const float4*)&b0[j0 + tx * 4];
    float ss = 0.f;
#pragma unroll
    for (int ii = 0; ii < 4; ++ii) {
        int row = r0 + ty * 4 + ii;
        float4 v;
        v.x = acc[ii][0] + bb.x;
        v.y = acc[ii][1] + bb.y;
        v.z = acc[ii][2] + bb.z;
        v.w = acc[ii][3] + bb.w;
        *(float4*)&Xh[(size_t)row * HH + j0 + tx * 4] = v;
        ss += v.x * v.x + v.y * v.y + v.z * v.z + v.w * v.w;
    }

    red[tid] = ss;
    __syncthreads();
    for (int s = 128; s > 0; s >>= 1) {
        if (tid < s) red[tid] += red[tid + s];
        __syncthreads();
    }
    if (tid == 0) normp[bx] = red[0];
}

// 4096 blocks. bt<512: diag-group tile (GEMM + relu + A + nnz). gb0 tiles build
// their adjacency tile in LDS from the edge list. Others stream zeros.
__global__ __launch_bounds__(256) void k_fused(const float* __restrict__ Xh,
                                               const float* __restrict__ normp,
                                               const float* __restrict__ prob,
                                               const int* __restrict__ ei,
                                               float* __restrict__ out,
                                               unsigned* __restrict__ meta) {
    __shared__ float As[16][68];
    __shared__ float Bs[16][68];
    __shared__ unsigned Atile[64 * 64];
    __shared__ float s_norm;
    __shared__ int s_cnt[4];

    int bt = blockIdx.x;
    int tid = threadIdx.x;

    if (bt < 512) {
        int gb = bt >> 6;
        int t  = bt & 63;
        int tm = t >> 3, tn = t & 7;
        int r0 = gb * NPG + tm * 64, c0 = gb * NPG + tn * 64;
        int tx = tid & 15, ty = tid >> 4;
        int li = tid & 63, kq = tid >> 6;

        // normsq = sum of the 128 per-block partials (L2-hit loads)
        {
            float* redf = (float*)As;
            redf[tid] = (tid < 128) ? normp[tid] : 0.f;
            __syncthreads();
            for (int s = 128; s > 0; s >>= 1) {
                if (tid < s) redf[tid] += redf[tid + s];
                __syncthreads();
            }
            if (tid == 0) s_norm = redf[0];
            __syncthreads();
        }

        // graph-0 tiles: build 64x64 adjacency count tile in LDS from edge list.
        // (src in [r0,r0+64) => src<512 => graph 0; setup guarantees dst in same
        //  graph, offsets[0]==0 so local==global indices for graph 0.)
        if (gb == 0) {
            int r0l = tm * 64, c0l = tn * 64;
            for (int i = tid; i < 4096; i += 256) Atile[i] = 0u;
            __syncthreads();
            const int4* s4 = (const int4*)ei;
            const int4* d4 = (const int4*)(ei + NE);
#pragma unroll 8
            for (int it = 0; it < NE / 4 / 256; ++it) {
                int4 s = s4[it * 256 + tid];
                int4 d = d4[it * 256 + tid];
                if ((unsigned)(s.x - r0l) < 64u && (unsigned)(d.x - c0l) < 64u)
                    atomicAdd(&Atile[(s.x - r0l) * 64 + (d.x - c0l)], 1u);
                if ((unsigned)(s.y - r0l) < 64u && (unsigned)(d.y - c0l) < 64u)
                    atomicAdd(&Atile[(s.y - r0l) * 64 + (d.y - c0l)], 1u);
                if ((unsigned)(s.z - r0l) < 64u && (unsigned)(d.z - c0l) < 64u)
                    atomicAdd(&Atile[(s.z - r0l) * 64 + (d.z - c0l)], 1u);
                if ((unsigned)(s.w - r0l) < 64u && (unsigned)(d.w - c0l) < 64u)
                    atomicAdd(&Atile[(s.w - r0l) * 64 + (d.w - c0l)], 1u);
            }
            __syncthreads();
        }

        float acc[4][4];
#pragma unroll
        for (int i = 0; i < 4; ++i)
#pragma unroll
            for (int j = 0; j < 4; ++j) acc[i][j] = 0.f;

        for (int k0 = 0; k0 < HH; k0 += 16) {
            float4 av = *(const float4*)&Xh[(size_t)(r0 + li) * HH + k0 + kq * 4];
            float4 bv = *(const float4*)&Xh[(size_t)(c0 + li) * HH + k0 + kq * 4];
            As[kq*4+0][li] = av.x; As[kq*4+1][li] = av.y;
            As[kq*4+2][li] = av.z; As[kq*4+3][li] = av.w;
            Bs[kq*4+0][li] = bv.x; Bs[kq*4+1][li] = bv.y;
            Bs[kq*4+2][li] = bv.z; Bs[kq*4+3][li] = bv.w;
            __syncthreads();
#pragma unroll
            for (int k = 0; k < 16; ++k) {
                float4 a = *(const float4*)&As[k][ty * 4];
                float4 b = *(const float4*)&Bs[k][tx * 4];
                float ar[4] = {a.x, a.y, a.z, a.w};
                float br[4] = {b.x, b.y, b.z, b.w};
#pragma unroll
                for (int i = 0; i < 4; ++i)
#pragma unroll
                    for (int j = 0; j < 4; ++j) acc[i][j] += ar[i] * br[j];
            }
            __syncthreads();
        }

        float inv = 1.0f / s_norm;
        float p = prob[0];
        int cnt = 0;
#pragma unroll
        for (int ii = 0; ii < 4; ++ii) {
            int lr = ty * 4 + ii;
            int row = r0 + lr;
            float4 v;
            float w[4];
#pragma unroll
            for (int jj = 0; jj < 4; ++jj) {
                int lc = tx * 4 + jj;
                float s = acc[ii][jj] * inv;
                float a = (gb == 0) ? (float)Atile[lr * 64 + lc] : 0.f;
                float pre = s - p + ALPHA * a;
                w[jj] = pre > 0.f ? pre : 0.f;
                cnt += (pre > 0.f) ? 1 : 0;
            }
            v.x = w[0]; v.y = w[1]; v.z = w[2]; v.w = w[3];
            *(float4*)&out[(size_t)row * NN + c0 + tx * 4] = v;
        }

        // nnz: wave reduce -> 4 leaders -> tid0; scoped-atomic finalize.
#pragma unroll
        for (int off = 32; off > 0; off >>= 1) cnt += __shfl_down(cnt, off);
        if ((tid & 63) == 0) s_cnt[tid >> 6] = cnt;
        __syncthreads();
        if (tid == 0) {
            unsigned total = (unsigned)(s_cnt[0] + s_cnt[1] + s_cnt[2] + s_cnt[3]);
            __hip_atomic_fetch_add(&meta[0], total, __ATOMIC_RELEASE,
                                   __HIP_MEMORY_SCOPE_AGENT);
            unsigned old = __hip_atomic_fetch_add(&meta[1], 1u, __ATOMIC_ACQ_REL,
                                                  __HIP_MEMORY_SCOPE_AGENT);
            if (old == 511u) {
                unsigned nzt = __hip_atomic_load(&meta[0], __ATOMIC_ACQUIRE,
                                                 __HIP_MEMORY_SCOPE_AGENT);
                out[(size_t)NN * NN]     = (float)nzt / (float)NE;
                out[(size_t)NN * NN + 1] = prob[0];
            }
        }
    } else {
        // off-diagonal zero tile
        int idx = bt - 512;                      // [0, 3584)
        int tr = idx / 56;
        int k  = idx - tr * 56;
        int grp = tr >> 3;
        int tc = (k >= grp * 8) ? (k + 8) : k;
        int r0 = tr * 64, c0 = tc * 64;
        float4 z = make_float4(0.f, 0.f, 0.f, 0.f);
        int row = r0 + (tid >> 4);
        int col = c0 + (tid & 15) * 4;
#pragma unroll
        for (int ii = 0; ii < 4; ++ii)
            *(float4*)&out[(size_t)(row + ii * 16) * NN + col] = z;
    }
}

extern "C" void kernel_launch(void* const* d_in, const int* in_sizes, int n_in,
                              void* d_out, int out_size, void* d_ws, size_t ws_size,
                              hipStream_t stream) {
    (void)in_sizes; (void)n_in; (void)out_size; (void)ws_size;
    const float* x    = (const float*)d_in[0];
    const float* W0   = (const float*)d_in[1];
    const float* b0   = (const float*)d_in[2];
    const float* prob = (const float*)d_in[3];
    const int*   ei   = (const int*)d_in[4];
    float* out = (float*)d_out;
    char*  ws  = (char*)d_ws;

    unsigned* meta  = (unsigned*)ws;
    float*    normp = (float*)(ws + NORMP_OFF);
    float*    Xh    = (float*)(ws + XH_OFF);

    k_xhat<<<129, 256, 0, stream>>>(x, W0, b0, Xh, normp, meta);
    k_fused<<<4096, 256, 0, stream>>>(Xh, normp, prob, ei, out, meta);
}

// Round 6
// 152.958 us; speedup vs baseline: 1.1280x; 1.1280x over previous
//
#include <hip/hip_runtime.h>

// SimGRew: Wmat = relu(S - prob + 0.5*A_sel) * same-graph-block mask
//   S = (X_hat @ X_hat^T) / ||X_hat||_F^2,  X_hat = x @ W0^T + b0
//   A_sel[i,j] = A[batch[i], i, j] (local-index adjacency) -> nonzero only for
//   i,j < NPG: ONLY graph 0's diagonal block sees the +alpha*A term.
// Outputs flat: Wmat[N*N] f32, edge_ratio, prob.
//
// R6: R5 structure MINUS the agent-scope release/acq_rel finalize (R5 showed
// 512 L2-writeback-bearing atomics serialize the XCDs: k_fused 109us @ 8.6%
// occupancy). nnz goes to per-block slots; tiny k_fin reduces them. Kernel
// boundaries are the only fences. 3 dispatches.

#define NN   4096
#define GG   8
#define NPG  512
#define FF   128
#define HH   128
#define NE   131072
#define ALPHA 0.5f

// ws layout (bytes):
//   [64,576)     normp  float[128]   (per-xhat-block norm partials)
//   [1024,3072)  nzp    int[512]     (per-diag-block nnz, all written)
//   [4096,+2MB)  Xh     float[NN*HH]
#define NORMP_OFF 64
#define NZP_OFF   1024
#define XH_OFF    4096

// 128 blocks: X_hat 64x64 tiles -> Xh, norm partial -> normp[bx].
__global__ __launch_bounds__(256) void k_xhat(const float* __restrict__ x,
                                              const float* __restrict__ W0,
                                              const float* __restrict__ b0,
                                              float* __restrict__ Xh,
                                              float* __restrict__ normp) {
    int bx = blockIdx.x;
    int tid = threadIdx.x;

    __shared__ float As[16][68];
    __shared__ float Bs[16][68];
    __shared__ float red[256];

    int tm = bx >> 1, tn = bx & 1;
    int r0 = tm * 64, j0 = tn * 64;
    int tx = tid & 15, ty = tid >> 4;
    int li = tid & 63, kq = tid >> 6;

    float acc[4][4];
#pragma unroll
    for (int i = 0; i < 4; ++i)
#pragma unroll
        for (int j = 0; j < 4; ++j) acc[i][j] = 0.f;

    for (int k0 = 0; k0 < FF; k0 += 16) {
        float4 av = *(const float4*)&x [(size_t)(r0 + li) * FF + k0 + kq * 4];
        float4 bv = *(const float4*)&W0[(size_t)(j0 + li) * FF + k0 + kq * 4];
        As[kq*4+0][li] = av.x; As[kq*4+1][li] = av.y;
        As[kq*4+2][li] = av.z; As[kq*4+3][li] = av.w;
        Bs[kq*4+0][li] = bv.x; Bs[kq*4+1][li] = bv.y;
        Bs[kq*4+2][li] = bv.z; Bs[kq*4+3][li] = bv.w;
        __syncthreads();
#pragma unroll
        for (int k = 0; k < 16; ++k) {
            float4 a = *(const float4*)&As[k][ty * 4];
            float4 b = *(const float4*)&Bs[k][tx * 4];
            float ar[4] = {a.x, a.y, a.z, a.w};
            float br[4] = {b.x, b.y, b.z, b.w};
#pragma unroll
            for (int i = 0; i < 4; ++i)
#pragma unroll
                for (int j = 0; j < 4; ++j) acc[i][j] += ar[i] * br[j];
        }
        __syncthreads();
    }

    float4 bb = *(const float4*)&b0[j0 + tx * 4];
    float ss = 0.f;
#pragma unroll
    for (int ii = 0; ii < 4; ++ii) {
        int row = r0 + ty * 4 + ii;
        float4 v;
        v.x = acc[ii][0] + bb.x;
        v.y = acc[ii][1] + bb.y;
        v.z = acc[ii][2] + bb.z;
        v.w = acc[ii][3] + bb.w;
        *(float4*)&Xh[(size_t)row * HH + j0 + tx * 4] = v;
        ss += v.x * v.x + v.y * v.y + v.z * v.z + v.w * v.w;
    }

    red[tid] = ss;
    __syncthreads();
    for (int s = 128; s > 0; s >>= 1) {
        if (tid < s) red[tid] += red[tid + s];
        __syncthreads();
    }
    if (tid == 0) normp[bx] = red[0];
}

// 4096 blocks. bt<512: diag-group tile (GEMM + relu + A + nnz->nzp[bt]).
// gb0 tiles build their 64x64 adjacency tile in LDS from the edge list.
// Others stream zeros. NO ordered atomics anywhere.
__global__ __launch_bounds__(256) void k_fused(const float* __restrict__ Xh,
                                               const float* __restrict__ normp,
                                               const float* __restrict__ prob,
                                               const int* __restrict__ ei,
                                               float* __restrict__ out,
                                               int* __restrict__ nzp) {
    __shared__ float As[16][68];
    __shared__ float Bs[16][68];
    __shared__ unsigned Atile[64 * 64];
    __shared__ float s_norm;
    __shared__ int s_cnt[4];

    int bt = blockIdx.x;
    int tid = threadIdx.x;

    if (bt < 512) {
        int gb = bt >> 6;
        int t  = bt & 63;
        int tm = t >> 3, tn = t & 7;
        int r0 = gb * NPG + tm * 64, c0 = gb * NPG + tn * 64;
        int tx = tid & 15, ty = tid >> 4;
        int li = tid & 63, kq = tid >> 6;

        // normsq = sum of 128 per-block partials (L2-hit loads)
        {
            float* redf = (float*)As;
            redf[tid] = (tid < 128) ? normp[tid] : 0.f;
            __syncthreads();
            for (int s = 128; s > 0; s >>= 1) {
                if (tid < s) redf[tid] += redf[tid + s];
                __syncthreads();
            }
            if (tid == 0) s_norm = redf[0];
            __syncthreads();
        }

        // graph-0 tiles: build 64x64 adjacency count tile in LDS from edges.
        // src window [r0l,r0l+64) subset of [0,512) => graph 0; offs[0]==0 so
        // local == global indices. dst window similarly graph-0 cols.
        if (gb == 0) {
            int r0l = tm * 64, c0l = tn * 64;
            for (int i = tid; i < 4096; i += 256) Atile[i] = 0u;
            __syncthreads();
            const int4* s4 = (const int4*)ei;
            const int4* d4 = (const int4*)(ei + NE);
#pragma unroll 8
            for (int it = 0; it < NE / 4 / 256; ++it) {
                int4 s = s4[it * 256 + tid];
                int4 d = d4[it * 256 + tid];
                if ((unsigned)(s.x - r0l) < 64u && (unsigned)(d.x - c0l) < 64u)
                    atomicAdd(&Atile[(s.x - r0l) * 64 + (d.x - c0l)], 1u);
                if ((unsigned)(s.y - r0l) < 64u && (unsigned)(d.y - c0l) < 64u)
                    atomicAdd(&Atile[(s.y - r0l) * 64 + (d.y - c0l)], 1u);
                if ((unsigned)(s.z - r0l) < 64u && (unsigned)(d.z - c0l) < 64u)
                    atomicAdd(&Atile[(s.z - r0l) * 64 + (d.z - c0l)], 1u);
                if ((unsigned)(s.w - r0l) < 64u && (unsigned)(d.w - c0l) < 64u)
                    atomicAdd(&Atile[(s.w - r0l) * 64 + (d.w - c0l)], 1u);
            }
            __syncthreads();
        }

        float acc[4][4];
#pragma unroll
        for (int i = 0; i < 4; ++i)
#pragma unroll
            for (int j = 0; j < 4; ++j) acc[i][j] = 0.f;

        for (int k0 = 0; k0 < HH; k0 += 16) {
            float4 av = *(const float4*)&Xh[(size_t)(r0 + li) * HH + k0 + kq * 4];
            float4 bv = *(const float4*)&Xh[(size_t)(c0 + li) * HH + k0 + kq * 4];
            As[kq*4+0][li] = av.x; As[kq*4+1][li] = av.y;
            As[kq*4+2][li] = av.z; As[kq*4+3][li] = av.w;
            Bs[kq*4+0][li] = bv.x; Bs[kq*4+1][li] = bv.y;
            Bs[kq*4+2][li] = bv.z; Bs[kq*4+3][li] = bv.w;
            __syncthreads();
#pragma unroll
            for (int k = 0; k < 16; ++k) {
                float4 a = *(const float4*)&As[k][ty * 4];
                float4 b = *(const float4*)&Bs[k][tx * 4];
                float ar[4] = {a.x, a.y, a.z, a.w};
                float br[4] = {b.x, b.y, b.z, b.w};
#pragma unroll
                for (int i = 0; i < 4; ++i)
#pragma unroll
                    for (int j = 0; j < 4; ++j) acc[i][j] += ar[i] * br[j];
            }
            __syncthreads();
        }

        float inv = 1.0f / s_norm;
        float p = prob[0];
        int cnt = 0;
#pragma unroll
        for (int ii = 0; ii < 4; ++ii) {
            int lr = ty * 4 + ii;
            int row = r0 + lr;
            float4 v;
            float w[4];
#pragma unroll
            for (int jj = 0; jj < 4; ++jj) {
                int lc = tx * 4 + jj;
                float s = acc[ii][jj] * inv;
                float a = (gb == 0) ? (float)Atile[lr * 64 + lc] : 0.f;
                float pre = s - p + ALPHA * a;
                w[jj] = pre > 0.f ? pre : 0.f;
                cnt += (pre > 0.f) ? 1 : 0;
            }
            v.x = w[0]; v.y = w[1]; v.z = w[2]; v.w = w[3];
            *(float4*)&out[(size_t)row * NN + c0 + tx * 4] = v;
        }

        // nnz: wave shuffle reduce -> 4 leaders -> plain store to nzp[bt]
#pragma unroll
        for (int off = 32; off > 0; off >>= 1) cnt += __shfl_down(cnt, off);
        if ((tid & 63) == 0) s_cnt[tid >> 6] = cnt;
        __syncthreads();
        if (tid == 0) nzp[bt] = s_cnt[0] + s_cnt[1] + s_cnt[2] + s_cnt[3];
    } else {
        // off-diagonal zero tile
        int idx = bt - 512;                      // [0, 3584)
        int tr = idx / 56;
        int k  = idx - tr * 56;
        int grp = tr >> 3;
        int tc = (k >= grp * 8) ? (k + 8) : k;
        int r0 = tr * 64, c0 = tc * 64;
        float4 z = make_float4(0.f, 0.f, 0.f, 0.f);
        int row = r0 + (tid >> 4);
        int col = c0 + (tid & 15) * 4;
#pragma unroll
        for (int ii = 0; ii < 4; ++ii)
            *(float4*)&out[(size_t)(row + ii * 16) * NN + col] = z;
    }
}

__global__ __launch_bounds__(256) void k_fin(const int* __restrict__ nzp,
                                             const float* __restrict__ prob,
                                             float* __restrict__ out) {
    __shared__ int red[256];
    int tid = threadIdx.x;
    red[tid] = nzp[tid] + nzp[tid + 256];
    __syncthreads();
    for (int s = 128; s > 0; s >>= 1) {
        if (tid < s) red[tid] += red[tid + s];
        __syncthreads();
    }
    if (tid == 0) {
        out[(size_t)NN * NN]     = (float)red[0] / (float)NE;
        out[(size_t)NN * NN + 1] = prob[0];
    }
}

extern "C" void kernel_launch(void* const* d_in, const int* in_sizes, int n_in,
                              void* d_out, int out_size, void* d_ws, size_t ws_size,
                              hipStream_t stream) {
    (void)in_sizes; (void)n_in; (void)out_size; (void)ws_size;
    const float* x    = (const float*)d_in[0];
    const float* W0   = (const float*)d_in[1];
    const float* b0   = (const float*)d_in[2];
    const float* prob = (const float*)d_in[3];
    const int*   ei   = (const int*)d_in[4];
    float* out = (float*)d_out;
    char*  ws  = (char*)d_ws;

    float* normp = (float*)(ws + NORMP_OFF);
    int*   nzp   = (int*)(ws + NZP_OFF);
    float* Xh    = (float*)(ws + XH_OFF);

    k_xhat<<<128, 256, 0, stream>>>(x, W0, b0, Xh, normp);
    k_fused<<<4096, 256, 0, stream>>>(Xh, normp, prob, ei, out, nzp);
    k_fin<<<1, 256, 0, stream>>>(nzp, prob, out);
}

// Round 7
// 110.961 us; speedup vs baseline: 1.5549x; 1.3785x over previous
//
#include <hip/hip_runtime.h>

// SimGRew: Wmat = relu(S - prob + 0.5*A_sel) * same-graph-block mask
//   S = (X_hat @ X_hat^T) / ||X_hat||_F^2,  X_hat = x @ W0^T + b0
//   A_sel[i,j] = A[batch[i], i, j] (local-index adjacency) -> nonzero only
//   i,j < NPG: ONLY graph 0's diagonal block sees the +alpha*A term.
// Outputs flat: Wmat[N*N] f32, edge_ratio, prob.
//
// R7: 4 dispatches. R6's in-fused edge scan removed (latency-serialized: 64
// blocks crawling 1MB at 1600cyc/iter = 90us tail @ 7.7% occupancy). D1 zeros
// the WHOLE output linearly (fill-pattern, ~6TB/s) while xhat GEMM runs in the
// same grid; D2 = R4-style parallel scatter (512 blocks, relaxed atomics);
// D3 = pure 512-block diag GEMM (small LDS, high occupancy); D4 = finalize.
// No ordered atomics anywhere (R2/R5 lesson: they trigger L2 writeback storms).

#define NN   4096
#define GG   8
#define NPG  512
#define FF   128
#define HH   128
#define NE   131072
#define ALPHA 0.5f

// ws layout (bytes):
//   [0, 1MiB)       Acnt   int[NPG*NPG]  (graph-0 adjacency counts)
//   [1MiB+64, +576) normp  float[128]
//   [1MiB+576)      normsq float
//   [1MiB+1024)     nzp    int[512]
//   [1MiB+4096)     Xh     float[NN*HH]  (2 MiB)
#define ACNT_BYTES ((size_t)NPG * NPG * 4)
#define NORMP_OFF  (ACNT_BYTES + 64)
#define NORMS_OFF  (ACNT_BYTES + 576)
#define NZP_OFF    (ACNT_BYTES + 1024)
#define XH_OFF     (ACNT_BYTES + 4096)

// D1: blocks 0..127 xhat tiles; 128..191 zero Acnt; 192..2239 zero out (linear).
__global__ __launch_bounds__(256) void k_prep(const float* __restrict__ x,
                                              const float* __restrict__ W0,
                                              const float* __restrict__ b0,
                                              float* __restrict__ Xh,
                                              float* __restrict__ normp,
                                              int* __restrict__ Acnt,
                                              float* __restrict__ out) {
    int bx = blockIdx.x;
    int tid = threadIdx.x;

    if (bx >= 192) {
        // linear zero of out[0 .. NN*NN): 2048 blocks x 32 KiB
        int zb = bx - 192;
        float4 z = make_float4(0.f, 0.f, 0.f, 0.f);
        float4* o4 = (float4*)out;
        size_t base = (size_t)zb * 2048 + tid;
#pragma unroll
        for (int k = 0; k < 8; ++k) o4[base + k * 256] = z;
        return;
    }
    if (bx >= 128) {
        // zero Acnt: 64 blocks x 16 KiB
        int zb = bx - 128;
        float4 z = make_float4(0.f, 0.f, 0.f, 0.f);
        float4* a4 = (float4*)Acnt;
#pragma unroll
        for (int k = 0; k < 4; ++k) a4[(size_t)zb * 1024 + tid + k * 256] = z;
        return;
    }

    // X_hat = x @ W0^T + b0 ; norm partial -> normp[bx]
    __shared__ float As[16][68];
    __shared__ float Bs[16][68];
    __shared__ float red[256];

    int tm = bx >> 1, tn = bx & 1;
    int r0 = tm * 64, j0 = tn * 64;
    int tx = tid & 15, ty = tid >> 4;
    int li = tid & 63, kq = tid >> 6;

    float acc[4][4];
#pragma unroll
    for (int i = 0; i < 4; ++i)
#pragma unroll
        for (int j = 0; j < 4; ++j) acc[i][j] = 0.f;

    for (int k0 = 0; k0 < FF; k0 += 16) {
        float4 av = *(const float4*)&x [(size_t)(r0 + li) * FF + k0 + kq * 4];
        float4 bv = *(const float4*)&W0[(size_t)(j0 + li) * FF + k0 + kq * 4];
        As[kq*4+0][li] = av.x; As[kq*4+1][li] = av.y;
        As[kq*4+2][li] = av.z; As[kq*4+3][li] = av.w;
        Bs[kq*4+0][li] = bv.x; Bs[kq*4+1][li] = bv.y;
        Bs[kq*4+2][li] = bv.z; Bs[kq*4+3][li] = bv.w;
        __syncthreads();
#pragma unroll
        for (int k = 0; k < 16; ++k) {
            float4 a = *(const float4*)&As[k][ty * 4];
            float4 b = *(const float4*)&Bs[k][tx * 4];
            float ar[4] = {a.x, a.y, a.z, a.w};
            float br[4] = {b.x, b.y, b.z, b.w};
#pragma unroll
            for (int i = 0; i < 4; ++i)
#pragma unroll
                for (int j = 0; j < 4; ++j) acc[i][j] += ar[i] * br[j];
        }
        __syncthreads();
    }

    float4 bb = *(const float4*)&b0[j0 + tx * 4];
    float ss = 0.f;
#pragma unroll
    for (int ii = 0; ii < 4; ++ii) {
        int row = r0 + ty * 4 + ii;
        float4 v;
        v.x = acc[ii][0] + bb.x;
        v.y = acc[ii][1] + bb.y;
        v.z = acc[ii][2] + bb.z;
        v.w = acc[ii][3] + bb.w;
        *(float4*)&Xh[(size_t)row * HH + j0 + tx * 4] = v;
        ss += v.x * v.x + v.y * v.y + v.z * v.z + v.w * v.w;
    }

    red[tid] = ss;
    __syncthreads();
    for (int s = 128; s > 0; s >>= 1) {
        if (tid < s) red[tid] += red[tid + s];
        __syncthreads();
    }
    if (tid == 0) normp[bx] = red[0];
}

// D2: blocks 0..511 scatter graph-0 edges (src<512 => graph 0, local==global);
//     block 512 reduces normp -> normsq.
__global__ __launch_bounds__(256) void k_scatter(const int* __restrict__ ei,
                                                 int* __restrict__ Acnt,
                                                 const float* __restrict__ normp,
                                                 float* __restrict__ normsq) {
    int bx = blockIdx.x;
    int tid = threadIdx.x;
    if (bx == 512) {
        __shared__ float red[128];
        if (tid < 128) red[tid] = normp[tid];
        __syncthreads();
        for (int s = 64; s > 0; s >>= 1) {
            if (tid < s) red[tid] += red[tid + s];
            __syncthreads();
        }
        if (tid == 0) *normsq = red[0];
        return;
    }
    int e = bx * 256 + tid;
    int src = ei[e], dst = ei[NE + e];
    if ((unsigned)src < (unsigned)NPG && (unsigned)dst < (unsigned)NPG)
        atomicAdd(&Acnt[src * NPG + dst], 1);
}

// D3: 512 diag-group tiles only. GEMM + relu + (gb0: +alpha*Acnt) + nnz->nzp.
__global__ __launch_bounds__(256) void k_diag(const float* __restrict__ Xh,
                                              const int* __restrict__ Acnt,
                                              const float* __restrict__ normsq,
                                              const float* __restrict__ prob,
                                              float* __restrict__ out,
                                              int* __restrict__ nzp) {
    __shared__ float As[16][68];
    __shared__ float Bs[16][68];
    __shared__ int s_cnt[4];

    int bt = blockIdx.x;
    int tid = threadIdx.x;
    int gb = bt >> 6;
    int t  = bt & 63;
    int tm = t >> 3, tn = t & 7;
    int r0 = gb * NPG + tm * 64, c0 = gb * NPG + tn * 64;
    int tx = tid & 15, ty = tid >> 4;
    int li = tid & 63, kq = tid >> 6;

    float acc[4][4];
#pragma unroll
    for (int i = 0; i < 4; ++i)
#pragma unroll
        for (int j = 0; j < 4; ++j) acc[i][j] = 0.f;

    for (int k0 = 0; k0 < HH; k0 += 16) {
        float4 av = *(const float4*)&Xh[(size_t)(r0 + li) * HH + k0 + kq * 4];
        float4 bv = *(const float4*)&Xh[(size_t)(c0 + li) * HH + k0 + kq * 4];
        As[kq*4+0][li] = av.x; As[kq*4+1][li] = av.y;
        As[kq*4+2][li] = av.z; As[kq*4+3][li] = av.w;
        Bs[kq*4+0][li] = bv.x; Bs[kq*4+1][li] = bv.y;
        Bs[kq*4+2][li] = bv.z; Bs[kq*4+3][li] = bv.w;
        __syncthreads();
#pragma unroll
        for (int k = 0; k < 16; ++k) {
            float4 a = *(const float4*)&As[k][ty * 4];
            float4 b = *(const float4*)&Bs[k][tx * 4];
            float ar[4] = {a.x, a.y, a.z, a.w};
            float br[4] = {b.x, b.y, b.z, b.w};
#pragma unroll
            for (int i = 0; i < 4; ++i)
#pragma unroll
                for (int j = 0; j < 4; ++j) acc[i][j] += ar[i] * br[j];
        }
        __syncthreads();
    }

    float inv = 1.0f / (*normsq);
    float p = prob[0];
    int cnt = 0;
#pragma unroll
    for (int ii = 0; ii < 4; ++ii) {
        int row = r0 + ty * 4 + ii;
        float4 v;
        float w[4];
#pragma unroll
        for (int jj = 0; jj < 4; ++jj) {
            int col = c0 + tx * 4 + jj;
            float s = acc[ii][jj] * inv;
            float a = (gb == 0) ? (float)Acnt[row * NPG + col] : 0.f;
            float pre = s - p + ALPHA * a;
            w[jj] = pre > 0.f ? pre : 0.f;
            cnt += (pre > 0.f) ? 1 : 0;
        }
        v.x = w[0]; v.y = w[1]; v.z = w[2]; v.w = w[3];
        *(float4*)&out[(size_t)row * NN + c0 + tx * 4] = v;
    }

    // nnz: wave shuffle reduce -> 4 leaders -> plain store
#pragma unroll
    for (int off = 32; off > 0; off >>= 1) cnt += __shfl_down(cnt, off);
    if ((tid & 63) == 0) s_cnt[tid >> 6] = cnt;
    __syncthreads();
    if (tid == 0) nzp[bt] = s_cnt[0] + s_cnt[1] + s_cnt[2] + s_cnt[3];
}

__global__ __launch_bounds__(256) void k_fin(const int* __restrict__ nzp,
                                             const float* __restrict__ prob,
                                             float* __restrict__ out) {
    __shared__ int red[256];
    int tid = threadIdx.x;
    red[tid] = nzp[tid] + nzp[tid + 256];
    __syncthreads();
    for (int s = 128; s > 0; s >>= 1) {
        if (tid < s) red[tid] += red[tid + s];
        __syncthreads();
    }
    if (tid == 0) {
        out[(size_t)NN * NN]     = (float)red[0] / (float)NE;
        out[(size_t)NN * NN + 1] = prob[0];
    }
}

extern "C" void kernel_launch(void* const* d_in, const int* in_sizes, int n_in,
                              void* d_out, int out_size, void* d_ws, size_t ws_size,
                              hipStream_t stream) {
    (void)in_sizes; (void)n_in; (void)out_size; (void)ws_size;
    const float* x    = (const float*)d_in[0];
    const float* W0   = (const float*)d_in[1];
    const float* b0   = (const float*)d_in[2];
    const float* prob = (const float*)d_in[3];
    const int*   ei   = (const int*)d_in[4];
    float* out = (float*)d_out;
    char*  ws  = (char*)d_ws;

    int*   Acnt   = (int*)ws;
    float* normp  = (float*)(ws + NORMP_OFF);
    float* normsq = (float*)(ws + NORMS_OFF);
    int*   nzp    = (int*)(ws + NZP_OFF);
    float* Xh     = (float*)(ws + XH_OFF);

    k_prep<<<2240, 256, 0, stream>>>(x, W0, b0, Xh, normp, Acnt, out);
    k_scatter<<<513, 256, 0, stream>>>(ei, Acnt, normp, normsq);
    k_diag<<<512, 256, 0, stream>>>(Xh, Acnt, normsq, prob, out, nzp);
    k_fin<<<1, 256, 0, stream>>>(nzp, prob, out);
}